// Round 4
// baseline (182.601 us; speedup 1.0000x reference)
//
#include <hip/hip_runtime.h>

typedef __attribute__((ext_vector_type(4))) float f32x4;
typedef __attribute__((ext_vector_type(8))) short bf16x8;

#define LOG2E 1.44269504088896340736f

__device__ __forceinline__ float bcf(unsigned u){ union{unsigned u;float f;}v; v.u=u; return v.f; }
__device__ __forceinline__ unsigned pkbf(float a, float b){
    unsigned w; asm("v_cvt_pk_bf16_f32 %0, %1, %2" : "=v"(w) : "v"(a), "v"(b)); return w;
}
__device__ __forceinline__ float ex2(float x){ return __builtin_amdgcn_exp2f(x); }
__device__ __forceinline__ float rcp_(float x){ return __builtin_amdgcn_rcpf(x); }

#define MFMA(a,b,c) __builtin_amdgcn_mfma_f32_16x16x32_bf16(a,b,c,0,0,0)

union FragU { unsigned w[4]; bf16x8 v; };

// split 8 f32 into hi/lo bf16 fragments
__device__ __forceinline__ void split8(const float* v, bf16x8 &fh, bf16x8 &fl){
    FragU H, L;
#pragma unroll
    for (int i=0;i<4;i++){
        unsigned w = pkbf(v[2*i], v[2*i+1]);
        H.w[i] = w;
        float ra = v[2*i]   - bcf(w<<16);
        float rb = v[2*i+1] - bcf(w & 0xffff0000u);
        L.w[i] = pkbf(ra, rb);
    }
    fh = H.v; fl = L.v;
}

// B-frag for packed x-MFMA: k = [xh(0-3), xl(4-7) | xh(8-11), 1@12, 1@13 | 0 | 0]
__device__ __forceinline__ void build_bx(const float4& x, int hi, FragU& B){
    unsigned w0 = pkbf(x.x, x.y), w1 = pkbf(x.z, x.w);
    float r0 = x.x - bcf(w0<<16), r1 = x.y - bcf(w0 & 0xffff0000u);
    float r2 = x.z - bcf(w1<<16), r3 = x.w - bcf(w1 & 0xffff0000u);
    unsigned l0 = pkbf(r0,r1), l1 = pkbf(r2,r3);
    const bool h01 = (hi < 2);
    B.w[0] = h01 ? w0 : 0u;
    B.w[1] = h01 ? w1 : 0u;
    B.w[2] = (hi==0) ? l0 : (hi==1 ? 0x3f803f80u : 0u);
    B.w[3] = (hi==0) ? l1 : 0u;
}

// single h value -> bf16 hi/lo halves at half-index col*40 + j (pitch 20 words)
__device__ __forceinline__ void put_h(unsigned* Hh, unsigned* Hl, int col, int j, float h){
    unsigned w  = pkbf(h, 0.0f);
    float  rr   = h - bcf(w << 16);
    unsigned lw = pkbf(rr, 0.0f);
    ((unsigned short*)Hh)[col*40 + j] = (unsigned short)w;
    ((unsigned short*)Hl)[col*40 + j] = (unsigned short)lw;
}

// ============================ main kernel: 4 waves x j-quarter ===================
__global__ __launch_bounds__(256) void lstm2_q(
    const float* __restrict__ xin,   // [8192,64,4]
    const float* __restrict__ sfc,   // [8192,5]
    const float* __restrict__ w_sfc1, const float* __restrict__ b_sfc1,
    const float* __restrict__ w_sfc2, const float* __restrict__ b_sfc2,
    const float* __restrict__ w_ih1, const float* __restrict__ w_hh1,
    const float* __restrict__ b_ih1, const float* __restrict__ b_hh1,
    const float* __restrict__ w_ih2, const float* __restrict__ w_hh2,
    const float* __restrict__ b_ih2, const float* __restrict__ b_hh2,
    const float* __restrict__ w_out, const float* __restrict__ b_out,
    float* __restrict__ outp,        // [8192,64,1]
    unsigned* __restrict__ ws)       // out1 history, 16384 uints per block
{
    __shared__ __align__(16) unsigned hbuf[2][2][16][20]; // [par][hi/lo][b][20w=40 halves]
    __shared__ float ybuf[4][64][16];

    const int tid  = threadIdx.x;
    const int wq   = tid >> 6;          // j-quarter
    const int lane = tid & 63;
    const int col  = lane & 15;         // batch col / A row
    const int hi   = lane >> 4;         // k-block; gate-row quad
    const int B0   = blockIdx.x * 16;
    unsigned* wsb  = ws + blockIdx.x * 16384;

    // A-row r = col encodes (jl = r>>2, gate g = r&3); chain c covers j = 8wq+4c+jl
    const int jl = col >> 2, g = col & 3;
    const float sc = (g == 2) ? (2.0f*LOG2E) : (-LOG2E);
    const int j0 = 8*wq + hi;           // this lane's chain-0 element j
    const int j1 = 8*wq + 4 + hi;       // chain-1 element j

    // ---------------- layer-1 weights ---------------------------------------------
    bf16x8 Whh_h[2], Whh_l[2], WxA[2];
#pragma unroll
    for (int c=0;c<2;c++){
        const int grow = g*32 + 8*wq + 4*c + jl;
        float wvv[8];
        float4 wa = *(const float4*)(w_hh1 + grow*32 + 8*hi);
        float4 wb = *(const float4*)(w_hh1 + grow*32 + 8*hi + 4);
        wvv[0]=wa.x*sc; wvv[1]=wa.y*sc; wvv[2]=wa.z*sc; wvv[3]=wa.w*sc;
        wvv[4]=wb.x*sc; wvv[5]=wb.y*sc; wvv[6]=wb.z*sc; wvv[7]=wb.w*sc;
        split8(wvv, Whh_h[c], Whh_l[c]);
        float4 wi = *(const float4*)(w_ih1 + grow*4);
        float wh0=wi.x*sc, wh1=wi.y*sc, wh2=wi.z*sc, wh3=wi.w*sc;
        unsigned xw0 = pkbf(wh0,wh1), xw1 = pkbf(wh2,wh3);
        float wl0 = wh0-bcf(xw0<<16), wl1 = wh1-bcf(xw0 & 0xffff0000u);
        float wl2 = wh2-bcf(xw1<<16), wl3 = wh3-bcf(xw1 & 0xffff0000u);
        unsigned lw0 = pkbf(wl0,wl1), lw1 = pkbf(wl2,wl3);
        float bias = (b_ih1[grow] + b_hh1[grow])*sc;
        unsigned bh = pkbf(bias, 0.0f);
        float blo = bias - bcf(bh<<16);
        unsigned bword = pkbf(bias, blo);
        FragU A;
        if (hi==0){ A.w[0]=xw0; A.w[1]=xw1; A.w[2]=xw0; A.w[3]=xw1; }
        else if (hi==1){ A.w[0]=lw0; A.w[1]=lw1; A.w[2]=bword; A.w[3]=0u; }
        else { A.w[0]=0u; A.w[1]=0u; A.w[2]=0u; A.w[3]=0u; }
        WxA[c] = A.v;
    }

    // ---------------- surface MLP -> h0, cs0 --------------------------------------
    float cs[2], hv[2];
    {
        const float* sp = sfc + (B0 + col)*5;
        const float s0=sp[0], s1=sp[1], s2=sp[2], s3=sp[3], s4=sp[4];
#pragma unroll
        for (int c=0;c<2;c++){
            const int j = 8*wq + 4*c + hi;
            float a1 = b_sfc1[j] + s0*w_sfc1[j*5+0] + s1*w_sfc1[j*5+1]
                     + s2*w_sfc1[j*5+2] + s3*w_sfc1[j*5+3] + s4*w_sfc1[j*5+4];
            float a2 = b_sfc2[j] + s0*w_sfc2[j*5+0] + s1*w_sfc2[j*5+1]
                     + s2*w_sfc2[j*5+2] + s3*w_sfc2[j*5+3] + s4*w_sfc2[j*5+4];
            hv[c] = 1.0f - 2.0f*rcp_(ex2((2.0f*LOG2E)*a1)+1.0f);
            cs[c] = (2.0f*LOG2E)*(1.0f - 2.0f*rcp_(ex2((2.0f*LOG2E)*a2)+1.0f));
        }
    }
    put_h(&hbuf[0][0][0][0], &hbuf[0][1][0][0], col, j0, hv[0]);
    put_h(&hbuf[0][0][0][0], &hbuf[0][1][0][0], col, j1, hv[1]);
    __syncthreads();

    // ---------------- phase 1: layer-1 LSTM, reversed time ------------------------
    int par = 0;
    FragU Bx;
    {
        float4 x0 = *(const float4*)(xin + ((B0 + col)*64 + 63)*4);
        build_bx(x0, hi, Bx);
    }
#pragma unroll 1
    for (int t=63; t>=0; --t){
        bf16x8 Hh = *(const bf16x8*)&hbuf[par][0][col][4*hi];
        bf16x8 Hl = *(const bf16x8*)&hbuf[par][1][col][4*hi];
        f32x4 acc[2];
#pragma unroll
        for (int c=0;c<2;c++){
            f32x4 a = {0.f,0.f,0.f,0.f};
            a = MFMA(WxA[c],   Bx.v, a);
            a = MFMA(Whh_h[c], Hh,   a);
            a = MFMA(Whh_h[c], Hl,   a);
            a = MFMA(Whh_l[c], Hh,   a);
            acc[c] = a;
        }
        if (t){
            float4 xn = *(const float4*)(xin + ((B0 + col)*64 + (t-1))*4);
            build_bx(xn, hi, Bx);
        }
        int q[2];
#pragma unroll
        for (int c=0;c<2;c++){
            float iv = acc[c][0], fv = acc[c][1], gv = acc[c][2], ov = acc[c][3];
            float si = rcp_(1.0f+ex2(iv));
            float sf = rcp_(1.0f+ex2(fv));
            float so = rcp_(1.0f+ex2(ov));
            float tg = 1.0f - 2.0f*rcp_(ex2(gv)+1.0f);
            cs[c] = fmaf(sf, cs[c], ((2.0f*LOG2E)*si)*tg);
            float tc = 1.0f - 2.0f*rcp_(ex2(cs[c])+1.0f);
            hv[c] = so*tc;
            q[c] = __float2int_rn(hv[c]*32767.0f);
        }
        put_h(&hbuf[par^1][0][0][0], &hbuf[par^1][1][0][0], col, j0, hv[0]);
        put_h(&hbuf[par^1][0][0][0], &hbuf[par^1][1][0][0], col, j1, hv[1]);
        // out1 history -> global: pair j's via xor-16 exchange, 1 dword per lane
        {
            int e0 = __shfl_xor(q[0], 16, 64);
            int e1 = __shfl_xor(q[1], 16, 64);
            unsigned val = (hi & 1)
                ? (((unsigned)e1 & 0xffffu) | ((unsigned)q[1] << 16))
                : (((unsigned)q[0] & 0xffffu) | ((unsigned)e0 << 16));
            const int word = 4*wq + 2*(hi & 1) + (hi >> 1);
            wsb[(t*16 + col)*16 + word] = val;
        }
        __syncthreads();
        par ^= 1;
    }

    // ---------------- layer-2 weights + bias --------------------------------------
    bf16x8 W2h_h[2], W2h_l[2], W2x_h[2], W2x_l[2];
#pragma unroll
    for (int c=0;c<2;c++){
        const int grow = g*32 + 8*wq + 4*c + jl;
        float wvv[8];
        {
            float4 wa = *(const float4*)(w_hh2 + grow*32 + 8*hi);
            float4 wb = *(const float4*)(w_hh2 + grow*32 + 8*hi + 4);
            wvv[0]=wa.x*sc; wvv[1]=wa.y*sc; wvv[2]=wa.z*sc; wvv[3]=wa.w*sc;
            wvv[4]=wb.x*sc; wvv[5]=wb.y*sc; wvv[6]=wb.z*sc; wvv[7]=wb.w*sc;
        }
        split8(wvv, W2h_h[c], W2h_l[c]);
        {
            const float scx = sc * (1.0f/32767.0f);
            float4 wa = *(const float4*)(w_ih2 + grow*32 + 8*hi);
            float4 wb = *(const float4*)(w_ih2 + grow*32 + 8*hi + 4);
            wvv[0]=wa.x*scx; wvv[1]=wa.y*scx; wvv[2]=wa.z*scx; wvv[3]=wa.w*scx;
            wvv[4]=wb.x*scx; wvv[5]=wb.y*scx; wvv[6]=wb.z*scx; wvv[7]=wb.w*scx;
        }
        split8(wvv, W2x_h[c], W2x_l[c]);
    }
    float bia[2][4], woutr[2];
#pragma unroll
    for (int c=0;c<2;c++){
        const int j = 8*wq + 4*c + hi;
#pragma unroll
        for (int p=0;p<4;p++){
            const float s = (p==2) ? (2.0f*LOG2E) : (-LOG2E);
            bia[c][p] = (b_ih2[p*32+j] + b_hh2[p*32+j]) * s;
        }
        woutr[c] = w_out[j];
        cs[c] = 0.0f;
    }
    // zero h2_{-1} in hbuf[par]
    put_h(&hbuf[par][0][0][0], &hbuf[par][1][0][0], col, j0, 0.0f);
    put_h(&hbuf[par][0][0][0], &hbuf[par][1][0][0], col, j1, 0.0f);
    // prefetch X(t=0)
    FragU Xh, Xl;
    {
        const uint4 xw = *(const uint4*)&wsb[(0*16 + col)*16 + 4*hi];
        float xv[8];
        xv[0]=(float)(short)(xw.x & 0xffffu); xv[1]=(float)((int)xw.x >> 16);
        xv[2]=(float)(short)(xw.y & 0xffffu); xv[3]=(float)((int)xw.y >> 16);
        xv[4]=(float)(short)(xw.z & 0xffffu); xv[5]=(float)((int)xw.z >> 16);
        xv[6]=(float)(short)(xw.w & 0xffffu); xv[7]=(float)((int)xw.w >> 16);
        split8(xv, Xh.v, Xl.v);
    }
    __syncthreads();

    // ---------------- phase 2: layer-2 LSTM + fused output ------------------------
#pragma unroll 1
    for (int t=0; t<64; ++t){
        bf16x8 Hh = *(const bf16x8*)&hbuf[par][0][col][4*hi];
        bf16x8 Hl = *(const bf16x8*)&hbuf[par][1][col][4*hi];
        f32x4 acc[2];
#pragma unroll
        for (int c=0;c<2;c++){
            f32x4 a = {0.f,0.f,0.f,0.f};
            a = MFMA(W2x_h[c], Xh.v, a);
            a = MFMA(W2x_h[c], Xl.v, a);
            a = MFMA(W2x_l[c], Xh.v, a);
            a = MFMA(W2h_h[c], Hh,   a);
            a = MFMA(W2h_h[c], Hl,   a);
            a = MFMA(W2h_l[c], Hh,   a);
            acc[c] = a;
        }
        const int tn = (t < 63) ? t+1 : 63;
        const uint4 xw = *(const uint4*)&wsb[(tn*16 + col)*16 + 4*hi];

        float y = 0.0f;
#pragma unroll
        for (int c=0;c<2;c++){
            float iv = acc[c][0] + bia[c][0];
            float fv = acc[c][1] + bia[c][1];
            float gv = acc[c][2] + bia[c][2];
            float ov = acc[c][3] + bia[c][3];
            float si = rcp_(1.0f+ex2(iv));
            float sf = rcp_(1.0f+ex2(fv));
            float so = rcp_(1.0f+ex2(ov));
            float tg = 1.0f - 2.0f*rcp_(ex2(gv)+1.0f);
            cs[c] = fmaf(sf, cs[c], ((2.0f*LOG2E)*si)*tg);
            float tc = 1.0f - 2.0f*rcp_(ex2(cs[c])+1.0f);
            hv[c] = so*tc;
            y = fmaf(hv[c], woutr[c], y);
        }
        y += __shfl_xor(y, 16, 64);
        y += __shfl_xor(y, 32, 64);
        if (hi == 0) ybuf[wq][t][col] = y;
        put_h(&hbuf[par^1][0][0][0], &hbuf[par^1][1][0][0], col, j0, hv[0]);
        put_h(&hbuf[par^1][0][0][0], &hbuf[par^1][1][0][0], col, j1, hv[1]);
        {
            float xv[8];
            xv[0]=(float)(short)(xw.x & 0xffffu); xv[1]=(float)((int)xw.x >> 16);
            xv[2]=(float)(short)(xw.y & 0xffffu); xv[3]=(float)((int)xw.y >> 16);
            xv[4]=(float)(short)(xw.z & 0xffffu); xv[5]=(float)((int)xw.z >> 16);
            xv[6]=(float)(short)(xw.w & 0xffffu); xv[7]=(float)((int)xw.w >> 16);
            split8(xv, Xh.v, Xl.v);
        }
        __syncthreads();
        par ^= 1;
    }

    // ---------------- epilogue: sum quarter partials, coalesced store -------------
    const float bo = b_out[0];
    const int bb = tid >> 4;
    const int t0 = (tid & 15) * 4;
    float4 v;
    v.x = ybuf[0][t0+0][bb]+ybuf[1][t0+0][bb]+ybuf[2][t0+0][bb]+ybuf[3][t0+0][bb]+bo;
    v.y = ybuf[0][t0+1][bb]+ybuf[1][t0+1][bb]+ybuf[2][t0+1][bb]+ybuf[3][t0+1][bb]+bo;
    v.z = ybuf[0][t0+2][bb]+ybuf[1][t0+2][bb]+ybuf[2][t0+2][bb]+ybuf[3][t0+2][bb]+bo;
    v.w = ybuf[0][t0+3][bb]+ybuf[1][t0+3][bb]+ybuf[2][t0+3][bb]+ybuf[3][t0+3][bb]+bo;
    *(float4*)(outp + (B0 + bb)*64 + t0) = v;
}

// ============================ fallback (R3, proven): used if ws too small =========
__device__ __forceinline__ void write_h_pair(unsigned (*hb)[16][20], int b15, int hi, int wv_,
                                             const float* hvv){
    unsigned h0 = pkbf(hvv[0], hvv[1]);
    unsigned h1 = pkbf(hvv[2], hvv[3]);
    float r0 = hvv[0]-bcf(h0<<16), r1 = hvv[1]-bcf(h0 & 0xffff0000u);
    float r2 = hvv[2]-bcf(h1<<16), r3 = hvv[3]-bcf(h1 & 0xffff0000u);
    unsigned l0 = pkbf(r0,r1), l1 = pkbf(r2,r3);
    const int wi = 8*wv_ + 2*hi;
    *(uint2*)&hb[0][b15][wi] = make_uint2(h0,h1);
    *(uint2*)&hb[1][b15][wi] = make_uint2(l0,l1);
}

__global__ __launch_bounds__(128) void lstm2_fb(
    const float* __restrict__ xin, const float* __restrict__ sfc,
    const float* __restrict__ w_sfc1, const float* __restrict__ b_sfc1,
    const float* __restrict__ w_sfc2, const float* __restrict__ b_sfc2,
    const float* __restrict__ w_ih1, const float* __restrict__ w_hh1,
    const float* __restrict__ b_ih1, const float* __restrict__ b_hh1,
    const float* __restrict__ w_ih2, const float* __restrict__ w_hh2,
    const float* __restrict__ b_ih2, const float* __restrict__ b_hh2,
    const float* __restrict__ w_out, const float* __restrict__ b_out,
    float* __restrict__ outp)
{
    __shared__ __align__(16) unsigned out1q[64][16][16];
    __shared__ __align__(16) unsigned hbuf[2][2][16][20];
    __shared__ float ybuf[2][64][16];
    const int tid  = threadIdx.x;
    const int wv   = tid >> 6;
    const int lane = tid & 63;
    const int b15  = lane & 15;
    const int hi   = (lane >> 4) & 3;
    const int B0   = blockIdx.x * 16;
    bf16x8 Whh_h[4], Whh_l[4], WxA[4];
    bf16x8 W2h_h[4], W2h_l[4], W2x_h[4], W2x_l[4];
    float bia[4][4], woutr[4];
#pragma unroll
    for (int c=0;c<4;c++){
        const int gr = 32*c + 16*wv + b15;
        const float sc = (c==2) ? (2.0f*LOG2E) : (-LOG2E);
        float wvv[8];
        {
            float4 wa = *(const float4*)(w_hh1 + gr*32 + 8*hi);
            float4 wb = *(const float4*)(w_hh1 + gr*32 + 8*hi + 4);
            wvv[0]=wa.x*sc; wvv[1]=wa.y*sc; wvv[2]=wa.z*sc; wvv[3]=wa.w*sc;
            wvv[4]=wb.x*sc; wvv[5]=wb.y*sc; wvv[6]=wb.z*sc; wvv[7]=wb.w*sc;
        }
        split8(wvv, Whh_h[c], Whh_l[c]);
        {
            float4 wi = *(const float4*)(w_ih1 + gr*4);
            float wh0=wi.x*sc, wh1=wi.y*sc, wh2=wi.z*sc, wh3=wi.w*sc;
            unsigned xw0 = pkbf(wh0,wh1), xw1 = pkbf(wh2,wh3);
            float wl0 = wh0-bcf(xw0<<16), wl1 = wh1-bcf(xw0 & 0xffff0000u);
            float wl2 = wh2-bcf(xw1<<16), wl3 = wh3-bcf(xw1 & 0xffff0000u);
            unsigned lw0 = pkbf(wl0,wl1), lw1 = pkbf(wl2,wl3);
            float bias = (b_ih1[gr] + b_hh1[gr])*sc;
            unsigned bh = pkbf(bias, 0.0f);
            float blo = bias - bcf(bh<<16);
            unsigned bword = pkbf(bias, blo);
            FragU A;
            if (hi==0){ A.w[0]=xw0; A.w[1]=xw1; A.w[2]=xw0; A.w[3]=xw1; }
            else if (hi==1){ A.w[0]=lw0; A.w[1]=lw1; A.w[2]=bword; A.w[3]=0u; }
            else { A.w[0]=0u; A.w[1]=0u; A.w[2]=0u; A.w[3]=0u; }
            WxA[c] = A.v;
        }
        {
            float4 wa = *(const float4*)(w_hh2 + gr*32 + 8*hi);
            float4 wb = *(const float4*)(w_hh2 + gr*32 + 8*hi + 4);
            wvv[0]=wa.x*sc; wvv[1]=wa.y*sc; wvv[2]=wa.z*sc; wvv[3]=wa.w*sc;
            wvv[4]=wb.x*sc; wvv[5]=wb.y*sc; wvv[6]=wb.z*sc; wvv[7]=wb.w*sc;
        }
        split8(wvv, W2h_h[c], W2h_l[c]);
        {
            const float scx = sc * (1.0f/32767.0f);
            float4 wa = *(const float4*)(w_ih2 + gr*32 + 8*hi);
            float4 wb = *(const float4*)(w_ih2 + gr*32 + 8*hi + 4);
            wvv[0]=wa.x*scx; wvv[1]=wa.y*scx; wvv[2]=wa.z*scx; wvv[3]=wa.w*scx;
            wvv[4]=wb.x*scx; wvv[5]=wb.y*scx; wvv[6]=wb.z*scx; wvv[7]=wb.w*scx;
        }
        split8(wvv, W2x_h[c], W2x_l[c]);
    }
#pragma unroll
    for (int p=0;p<4;p++){
        const int j = 16*wv + 4*hi + p;
        bia[0][p] = (b_ih2[j]    + b_hh2[j])    * (-LOG2E);
        bia[1][p] = (b_ih2[32+j] + b_hh2[32+j]) * (-LOG2E);
        bia[2][p] = (b_ih2[64+j] + b_hh2[64+j]) * (2.0f*LOG2E);
        bia[3][p] = (b_ih2[96+j] + b_hh2[96+j]) * (-LOG2E);
        woutr[p]  = w_out[j];
    }
    float cs[4], hvv[4];
    {
        const float* sp = sfc + (B0 + b15)*5;
        const float s0=sp[0], s1=sp[1], s2=sp[2], s3=sp[3], s4=sp[4];
#pragma unroll
        for (int p=0;p<4;p++){
            const int j = 16*wv + 4*hi + p;
            float a1 = b_sfc1[j] + s0*w_sfc1[j*5+0] + s1*w_sfc1[j*5+1]
                     + s2*w_sfc1[j*5+2] + s3*w_sfc1[j*5+3] + s4*w_sfc1[j*5+4];
            float a2 = b_sfc2[j] + s0*w_sfc2[j*5+0] + s1*w_sfc2[j*5+1]
                     + s2*w_sfc2[j*5+2] + s3*w_sfc2[j*5+3] + s4*w_sfc2[j*5+4];
            hvv[p] = 1.0f - 2.0f*rcp_(ex2((2.0f*LOG2E)*a1)+1.0f);
            cs[p] = (2.0f*LOG2E)*(1.0f - 2.0f*rcp_(ex2((2.0f*LOG2E)*a2)+1.0f));
        }
    }
    write_h_pair(hbuf[0], b15, hi, wv, hvv);
    __syncthreads();
    int par = 0;
    FragU Bx;
    {
        float4 x0 = *(const float4*)(xin + ((B0 + b15)*64 + 63)*4);
        build_bx(x0, hi, Bx);
    }
#pragma unroll 1
    for (int t=63; t>=0; --t){
        bf16x8 Hh = *(const bf16x8*)&hbuf[par][0][b15][4*hi];
        bf16x8 Hl = *(const bf16x8*)&hbuf[par][1][b15][4*hi];
        f32x4 acc[4];
#pragma unroll
        for (int c=0;c<4;c++){
            f32x4 a = {0.f,0.f,0.f,0.f};
            a = MFMA(WxA[c],   Bx.v, a);
            a = MFMA(Whh_h[c], Hh,   a);
            a = MFMA(Whh_h[c], Hl,   a);
            a = MFMA(Whh_l[c], Hh,   a);
            acc[c] = a;
        }
        if (t){
            float4 xn = *(const float4*)(xin + ((B0 + b15)*64 + (t-1))*4);
            build_bx(xn, hi, Bx);
        }
        int q[4];
#pragma unroll
        for (int p=0;p<4;p++){
            float iv = acc[0][p], fv = acc[1][p], gv = acc[2][p], ov = acc[3][p];
            float si = rcp_(1.0f+ex2(iv));
            float sf = rcp_(1.0f+ex2(fv));
            float so = rcp_(1.0f+ex2(ov));
            float tg = 1.0f - 2.0f*rcp_(ex2(gv)+1.0f);
            cs[p] = fmaf(sf, cs[p], ((2.0f*LOG2E)*si)*tg);
            float tc = 1.0f - 2.0f*rcp_(ex2(cs[p])+1.0f);
            hvv[p] = so*tc;
            q[p] = __float2int_rn(hvv[p]*32767.0f);
        }
        unsigned q01 = ((unsigned)q[0] & 0xffffu) | ((unsigned)q[1] << 16);
        unsigned q23 = ((unsigned)q[2] & 0xffffu) | ((unsigned)q[3] << 16);
        *(uint2*)&out1q[t][b15][8*wv + 2*hi] = make_uint2(q01, q23);
        write_h_pair(hbuf[par^1], b15, hi, wv, hvv);
        __syncthreads();
        par ^= 1;
    }
    {
        const int wi = 8*wv + 2*hi;
        *(uint2*)&hbuf[par][0][b15][wi] = make_uint2(0u,0u);
        *(uint2*)&hbuf[par][1][b15][wi] = make_uint2(0u,0u);
        cs[0]=0.f; cs[1]=0.f; cs[2]=0.f; cs[3]=0.f;
    }
    FragU Xh, Xl;
    {
        const uint4 xw = *(const uint4*)&out1q[0][b15][4*hi];
        float xv[8];
        xv[0]=(float)(short)(xw.x & 0xffffu); xv[1]=(float)((int)xw.x >> 16);
        xv[2]=(float)(short)(xw.y & 0xffffu); xv[3]=(float)((int)xw.y >> 16);
        xv[4]=(float)(short)(xw.z & 0xffffu); xv[5]=(float)((int)xw.z >> 16);
        xv[6]=(float)(short)(xw.w & 0xffffu); xv[7]=(float)((int)xw.w >> 16);
        split8(xv, Xh.v, Xl.v);
    }
    __syncthreads();
#pragma unroll 1
    for (int t=0; t<64; ++t){
        bf16x8 Hh = *(const bf16x8*)&hbuf[par][0][b15][4*hi];
        bf16x8 Hl = *(const bf16x8*)&hbuf[par][1][b15][4*hi];
        f32x4 acc[4];
#pragma unroll
        for (int c=0;c<4;c++){
            f32x4 a = {0.f,0.f,0.f,0.f};
            a = MFMA(W2x_h[c], Xh.v, a);
            a = MFMA(W2x_h[c], Xl.v, a);
            a = MFMA(W2x_l[c], Xh.v, a);
            a = MFMA(W2h_h[c], Hh,   a);
            a = MFMA(W2h_h[c], Hl,   a);
            a = MFMA(W2h_l[c], Hh,   a);
            acc[c] = a;
        }
        const int tn = (t < 63) ? t+1 : 63;
        const uint4 xw = *(const uint4*)&out1q[tn][b15][4*hi];
        float y = 0.0f;
#pragma unroll
        for (int p=0;p<4;p++){
            float iv = acc[0][p] + bia[0][p];
            float fv = acc[1][p] + bia[1][p];
            float gv = acc[2][p] + bia[2][p];
            float ov = acc[3][p] + bia[3][p];
            float si = rcp_(1.0f+ex2(iv));
            float sf = rcp_(1.0f+ex2(fv));
            float so = rcp_(1.0f+ex2(ov));
            float tg = 1.0f - 2.0f*rcp_(ex2(gv)+1.0f);
            cs[p] = fmaf(sf, cs[p], ((2.0f*LOG2E)*si)*tg);
            float tc = 1.0f - 2.0f*rcp_(ex2(cs[p])+1.0f);
            hvv[p] = so*tc;
            y = fmaf(hvv[p], woutr[p], y);
        }
        y += __shfl_xor(y, 16, 64);
        y += __shfl_xor(y, 32, 64);
        if (hi == 0) ybuf[wv][t][b15] = y;
        write_h_pair(hbuf[par^1], b15, hi, wv, hvv);
        {
            float xv[8];
            xv[0]=(float)(short)(xw.x & 0xffffu); xv[1]=(float)((int)xw.x >> 16);
            xv[2]=(float)(short)(xw.y & 0xffffu); xv[3]=(float)((int)xw.y >> 16);
            xv[4]=(float)(short)(xw.z & 0xffffu); xv[5]=(float)((int)xw.z >> 16);
            xv[6]=(float)(short)(xw.w & 0xffffu); xv[7]=(float)((int)xw.w >> 16);
            split8(xv, Xh.v, Xl.v);
        }
        __syncthreads();
        par ^= 1;
    }
    const float bo = b_out[0];
    const int bb = tid >> 3;
    const int t0 = (tid & 7) * 8;
#pragma unroll
    for (int hlf=0; hlf<2; ++hlf){
        float4 v;
        v.x = ybuf[0][t0+4*hlf+0][bb] + ybuf[1][t0+4*hlf+0][bb] + bo;
        v.y = ybuf[0][t0+4*hlf+1][bb] + ybuf[1][t0+4*hlf+1][bb] + bo;
        v.z = ybuf[0][t0+4*hlf+2][bb] + ybuf[1][t0+4*hlf+2][bb] + bo;
        v.w = ybuf[0][t0+4*hlf+3][bb] + ybuf[1][t0+4*hlf+3][bb] + bo;
        *(float4*)(outp + (B0 + bb)*64 + t0 + 4*hlf) = v;
    }
}

extern "C" void kernel_launch(void* const* d_in, const int* in_sizes, int n_in,
                              void* d_out, int out_size, void* d_ws, size_t ws_size,
                              hipStream_t stream) {
    const float* xin    = (const float*)d_in[0];
    const float* sfc    = (const float*)d_in[1];
    const float* w_sfc1 = (const float*)d_in[2];
    const float* b_sfc1 = (const float*)d_in[3];
    const float* w_sfc2 = (const float*)d_in[4];
    const float* b_sfc2 = (const float*)d_in[5];
    const float* w_ih1  = (const float*)d_in[6];
    const float* w_hh1  = (const float*)d_in[7];
    const float* b_ih1  = (const float*)d_in[8];
    const float* b_hh1  = (const float*)d_in[9];
    const float* w_ih2  = (const float*)d_in[10];
    const float* w_hh2  = (const float*)d_in[11];
    const float* b_ih2  = (const float*)d_in[12];
    const float* b_hh2  = (const float*)d_in[13];
    const float* w_out  = (const float*)d_in[14];
    const float* b_out  = (const float*)d_in[15];
    float* out = (float*)d_out;

    const size_t need = 512ull * 65536ull;   // 32 MiB out1 history
    if (ws_size >= need) {
        hipLaunchKernelGGL(lstm2_q, dim3(512), dim3(256), 0, stream,
                           xin, sfc, w_sfc1, b_sfc1, w_sfc2, b_sfc2,
                           w_ih1, w_hh1, b_ih1, b_hh1,
                           w_ih2, w_hh2, b_ih2, b_hh2,
                           w_out, b_out, out, (unsigned*)d_ws);
    } else {
        hipLaunchKernelGGL(lstm2_fb, dim3(512), dim3(128), 0, stream,
                           xin, sfc, w_sfc1, b_sfc1, w_sfc2, b_sfc2,
                           w_ih1, w_hh1, b_ih1, b_hh1,
                           w_ih2, w_hh2, b_ih2, b_hh2,
                           w_out, b_out, out);
    }
}